// Round 1
// baseline (445.149 us; speedup 1.0000x reference)
//
#include <hip/hip_runtime.h>

// cReLU_percent: x (32,128,112,112) fp32. Per pixel (n,h,w): keep channel
// values that are >= the 64th-largest across C=128, then ReLU; zero the rest.
//
// Strategy: one thread = one pixel. 128 channel values per lane (stride
// HW=12544 floats, so loads are perfectly coalesced across the wave).
// Threshold = min of top-64 multiset via two bitonic 64-sorts + the bitonic
// split pairing max(A[i], B[63-i]). Originals are re-read (L2/L3-hot) for the
// masked store since the sort is in-place.

#define CC   128
#define HWSZ 12544   // 112*112, == 64*196 so wave tiles never straddle n

__device__ __forceinline__ void bitonic64(float v[64]) {
  #pragma unroll
  for (int k = 2; k <= 64; k <<= 1) {
    #pragma unroll
    for (int j = k >> 1; j > 0; j >>= 1) {
      #pragma unroll
      for (int i = 0; i < 64; ++i) {
        int l = i ^ j;
        if (l > i) {
          float lo = fminf(v[i], v[l]);
          float hi = fmaxf(v[i], v[l]);
          bool up = ((i & k) == 0);   // compile-time after unroll
          v[i] = up ? lo : hi;
          v[l] = up ? hi : lo;
        }
      }
    }
  }
}

__global__ __launch_bounds__(256) void crelu_pct_kernel(
    const float* __restrict__ x, float* __restrict__ out, int npix) {
  const int q = blockIdx.x * blockDim.x + threadIdx.x;  // flattened (n, h*w)
  if (q >= npix) return;
  const int n = q / HWSZ;
  const int p = q - n * HWSZ;
  const size_t base = (size_t)n * ((size_t)CC * HWSZ) + (size_t)p;
  const float* xp = x + base;
  float*       op = out + base;

  // ---- load + sort channels 0..63 ----
  float a[64];
  #pragma unroll
  for (int c = 0; c < 64; ++c) a[c] = xp[(size_t)c * HWSZ];
  bitonic64(a);

  // ---- load + sort channels 64..127 ----
  float b[64];
  #pragma unroll
  for (int c = 0; c < 64; ++c) b[c] = xp[(size_t)(c + 64) * HWSZ];
  bitonic64(b);

  // ---- 64th largest of A∪B: min over i of max(a[i], b[63-i]) ----
  float thr = fmaxf(a[0], b[63]);
  #pragma unroll
  for (int i = 1; i < 64; ++i) thr = fminf(thr, fmaxf(a[i], b[63 - i]));

  // ---- re-read originals (L2/L3-hot), apply mask + ReLU, store ----
  #pragma unroll
  for (int c = 0; c < CC; ++c) {
    float v = xp[(size_t)c * HWSZ];
    op[(size_t)c * HWSZ] = (v >= thr && v > 0.0f) ? v : 0.0f;
  }
}

extern "C" void kernel_launch(void* const* d_in, const int* in_sizes, int n_in,
                              void* d_out, int out_size, void* d_ws, size_t ws_size,
                              hipStream_t stream) {
  const float* x = (const float*)d_in[0];
  float* out = (float*)d_out;
  const int npix = in_sizes[0] / CC;        // 32*112*112 = 401408
  const int block = 256;
  const int grid = (npix + block - 1) / block;  // 1568
  crelu_pct_kernel<<<grid, block, 0, stream>>>(x, out, npix);
}

// Round 2
// 363.036 us; speedup vs baseline: 1.2262x; 1.2262x over previous
//
#include <hip/hip_runtime.h>

// cReLU_percent: x (32,128,112,112) fp32. Per pixel (n,h,w): keep channel
// values >= the 64th-largest across C=128, then ReLU; zero the rest.
//
// R2: lane-pair split. Lane 2i handles channels 0..63 of pixel q, lane 2i+1
// channels 64..127. Each lane bitonic-sorts its 64 values (ascending), then
// the pair merges via 64 __shfl_xor(1) steps using the bitonic-split
// identity: top-64 of A∪B = {max(a[i], b[63-i])}, threshold = min of that.
// 64 live sort regs/lane (vs 128 in R1) -> VGPR ~100 -> ~5 waves/SIMD to
// hide load latency. Originals re-read from L2/L3 for the masked store.

#define CC   128
#define HWSZ 12544   // 112*112; 32 pixels/wave-half never straddle n

__device__ __forceinline__ void bitonic64(float v[64]) {
  #pragma unroll
  for (int k = 2; k <= 64; k <<= 1) {
    #pragma unroll
    for (int j = k >> 1; j > 0; j >>= 1) {
      #pragma unroll
      for (int i = 0; i < 64; ++i) {
        int l = i ^ j;
        if (l > i) {
          float lo = fminf(v[i], v[l]);
          float hi = fmaxf(v[i], v[l]);
          bool up = ((i & k) == 0);   // compile-time after unroll
          v[i] = up ? lo : hi;
          v[l] = up ? hi : lo;
        }
      }
    }
  }
}

__global__ __launch_bounds__(256) void crelu_pct_kernel(
    const float* __restrict__ x, float* __restrict__ out) {
  const int t    = blockIdx.x * blockDim.x + threadIdx.x;
  const int q    = t >> 1;        // pixel index (n*HWSZ + p)
  const int half = t & 1;         // 0: channels 0..63, 1: channels 64..127
  const int n = q / HWSZ;
  const int p = q - n * HWSZ;
  const size_t base = (size_t)n * ((size_t)CC * HWSZ) + (size_t)p
                    + (size_t)(half << 6) * HWSZ;
  const float* xp = x + base;
  float*       op = out + base;

  // ---- load + sort this lane's 64 channels (ascending) ----
  float v[64];
  #pragma unroll
  for (int c = 0; c < 64; ++c) v[c] = xp[(size_t)c * HWSZ];
  bitonic64(v);

  // ---- pair merge: thr = min_i max(a[i], b[63-i]) via shfl_xor(1) ----
  // even lane sends a[i], odd lane sends b[63-i]; both compute identical thr.
  float thr;
  {
    float mine  = half ? v[63] : v[0];
    float other = __shfl_xor(mine, 1, 64);
    thr = fmaxf(mine, other);
    #pragma unroll
    for (int i = 1; i < 64; ++i) {
      float m  = half ? v[63 - i] : v[i];
      float o  = __shfl_xor(m, 1, 64);
      thr = fminf(thr, fmaxf(m, o));
    }
  }

  // ---- re-read originals (L2/L3-hot), apply mask + ReLU, store ----
  #pragma unroll
  for (int c = 0; c < 64; ++c) {
    float w = xp[(size_t)c * HWSZ];
    op[(size_t)c * HWSZ] = (w >= thr && w > 0.0f) ? w : 0.0f;
  }
}

extern "C" void kernel_launch(void* const* d_in, const int* in_sizes, int n_in,
                              void* d_out, int out_size, void* d_ws, size_t ws_size,
                              hipStream_t stream) {
  const float* x = (const float*)d_in[0];
  float* out = (float*)d_out;
  const int npix = in_sizes[0] / CC;            // 401408
  const int nthreads = npix * 2;                // 802816
  const int block = 256;
  const int grid = nthreads / block;            // 3136 exactly
  crelu_pct_kernel<<<grid, block, 0, stream>>>(x, out);
}